// Round 14
// baseline (211.881 us; speedup 1.0000x reference)
//
#include <hip/hip_runtime.h>
#include <hip/hip_bf16.h>
#include <math.h>

#define NB 512
#define NS 200
#define NH 256
#define TILE_S 32

typedef _Float16 f16x8 __attribute__((ext_vector_type(8)));
typedef float    f32x4 __attribute__((ext_vector_type(4)));

// LDS tile layout: unpadded [32][256] f16 rows with 16B-unit XOR swizzle
// unit' = unit ^ (row & 7) (R13; conflicts are not the binding constraint —
// R13 measured both layouts equivalent — kept because it also saves 3 KB LDS).
#define SWZ(r, u) ((((u) ^ ((r) & 7))) * 8)

// DPP-based add within each 16-lane row (VALU, not LDS port).
template<int CTRL>
__device__ __forceinline__ float dpp_xadd(float v) {
  return v + __int_as_float(
      __builtin_amdgcn_update_dpp(0, __float_as_int(v), CTRL, 0xf, 0xf, true));
}
// full 16-lane sum: quad_perm[1,0,3,2]=0xB1, quad_perm[2,3,0,1]=0x4E,
// row_ror:4=0x124, row_ror:8=0x128  (HW-verified in R2)
__device__ __forceinline__ float row16_sum(float v) {
  v = dpp_xadd<0xB1>(v);
  v = dpp_xadd<0x4E>(v);
  v = dpp_xadd<0x124>(v);
  v = dpp_xadd<0x128>(v);
  return v;
}

#define CVT_HL(idx, val) { const float x_ = (val); const _Float16 h_ = (_Float16)x_; \
                           ph[idx] = h_; pl[idx] = (_Float16)(x_ - (float)h_); }

// ---------------- single fused kernel: attention pool + projection per b -------
// grid 512 = one block per b (exactly 2 blocks/CU in ONE round — R11), 512
// threads = 8 waves x 32 n-cols. __launch_bounds__(512, 2): min-blocks-per-CU
// semantics (measured R2-R6); 128-reg cap, ~80 used.
// R8: hi/lo dual MFMA stream is the latency-hiding work — keep it.
// R10: no-max softmax (scores bounded |s|<~13 -> exp safe in fp32).
// R12: tail peeled (6 uniform tiles + 8-row tail). R13: XOR swizzle.
// R14: precompute kernel FOLDED IN — l = lastm@W^T computed in-block (proven
// fallback path), u_frag loaded straight from fp32 U (identical mapping +
// rounding). Prologue reordered: tile-0/1 global loads issued FIRST so their
// HBM latency hides under the l-dot and u_frag L3 loads. ws unused.
__global__ __launch_bounds__(512, 2)
void fused_attn(const float* __restrict__ mem,    // [B,S,H]
                const float* __restrict__ lastm,  // [B,H]
                const float* __restrict__ U,      // [H,H] fp32
                const float* __restrict__ W,      // [H,H] fp32
                const float* __restrict__ V,      // [H]
                const float* __restrict__ MetaW,  // [4,H]
                const float* __restrict__ Metab,  // [4]
                float* __restrict__ out)          // [B,4]
{
  const int b = blockIdx.x;

  const int t     = threadIdx.x;   // 0..511
  const int wave  = t >> 6;        // 0..7: owns n-cols [wave*32, wave*32+32)
  const int lane  = t & 63;
  const int m16   = lane & 15;
  const int quad  = lane >> 4;
  const int g     = t >> 5;        // 0..15: pooled row-pair {2g, 2g+1}
  const int u31   = t & 31;        // pooled / staging 16B-unit index

  __shared__ __align__(16) _Float16 hi_sm[2][TILE_S][NH];  // 32 KB
  __shared__ __align__(16) _Float16 lo_sm[2][TILE_S][NH];  // 32 KB
  __shared__ float swave_sm[8][TILE_S];
  __shared__ float e_sm[TILE_S];
  __shared__ float z_sm[1];
  __shared__ float l_sm[NH];
  __shared__ float lm_sm[NH];

  // ---- 1. issue tile-0 and tile-1 global loads FIRST (latency hidden under
  //         the l-dot and u_frag loads below) ----
  float4 a0, a1, b0, b1;          // tile 0
  float4 q00, q01, q10, q11;      // tile 1 (persists across iterations)
  {
    const float4* src4 = (const float4*)(mem + (size_t)b * NS * NH);
    a0 = src4[t * 2];         a1 = src4[t * 2 + 1];
    b0 = src4[(512 + t) * 2]; b1 = src4[(512 + t) * 2 + 1];
    const float4* nsrc = (const float4*)(mem + ((size_t)b * NS + TILE_S) * NH);
    q00 = nsrc[t * 2];         q01 = nsrc[t * 2 + 1];
    q10 = nsrc[(512 + t) * 2]; q11 = nsrc[(512 + t) * 2 + 1];
  }

  // ---- 2. in-block l = lastm[b] @ W^T (fp32, same order as old precompute) ----
  if (t < NH) lm_sm[t] = lastm[(size_t)b * NH + t];
  __syncthreads();
  if (t < NH) {
    const float4* wrow = (const float4*)(W + (size_t)t * NH);
    const float4* lrow = (const float4*)lm_sm;
    float c0 = 0.f, c1 = 0.f, c2 = 0.f, c3 = 0.f;
#pragma unroll 8
    for (int i = 0; i < NH / 4; ++i) {
      float4 w4 = wrow[i];
      float4 m4 = lrow[i];
      c0 = fmaf(w4.x, m4.x, c0);
      c1 = fmaf(w4.y, m4.y, c1);
      c2 = fmaf(w4.z, m4.z, c2);
      c3 = fmaf(w4.w, m4.w, c3);
    }
    l_sm[t] = (c0 + c1) + (c2 + c3);
  }
  __syncthreads();

  float l_reg[2], v_reg[2];
#pragma unroll
  for (int nf = 0; nf < 2; ++nf) {
    l_reg[nf] = l_sm[wave * 32 + nf * 16 + m16];
    v_reg[nf] = V[wave * 32 + nf * 16 + m16];
  }
  const float vsum  = v_reg[0] + v_reg[1];
  const float vm2_0 = -2.f * v_reg[0];
  const float vm2_1 = -2.f * v_reg[1];

  // ---- 3. U B-fragments straight from fp32 U (identical mapping/rounding to
  //         the old swizzled-fp16 path): row n, cols kk*32+quad*8..+7 ----
  f16x8 u_frag[2][8];
#pragma unroll
  for (int nf = 0; nf < 2; ++nf) {
    const int n = wave * 32 + nf * 16 + m16;
    const float* urow = U + (size_t)n * NH;
#pragma unroll
    for (int kk = 0; kk < 8; ++kk) {
      const float4 lo = *(const float4*)(urow + kk * 32 + quad * 8);
      const float4 hi = *(const float4*)(urow + kk * 32 + quad * 8 + 4);
      f16x8 f;
      f[0] = (_Float16)lo.x; f[1] = (_Float16)lo.y;
      f[2] = (_Float16)lo.z; f[3] = (_Float16)lo.w;
      f[4] = (_Float16)hi.x; f[5] = (_Float16)hi.y;
      f[6] = (_Float16)hi.z; f[7] = (_Float16)hi.w;
      u_frag[nf][kk] = f;
    }
  }

  // ---- 4. stage tile 0 into buffer 0 (loads from step 1 long since landed) ----
  {
    const int r0 = t >> 5, r1 = 16 + (t >> 5);
    {
      f16x8 ph, pl;
      CVT_HL(0, a0.x) CVT_HL(1, a0.y) CVT_HL(2, a0.z) CVT_HL(3, a0.w)
      CVT_HL(4, a1.x) CVT_HL(5, a1.y) CVT_HL(6, a1.z) CVT_HL(7, a1.w)
      *(f16x8*)&hi_sm[0][r0][SWZ(r0, u31)] = ph;
      *(f16x8*)&lo_sm[0][r0][SWZ(r0, u31)] = pl;
    }
    {
      f16x8 ph, pl;
      CVT_HL(0, b0.x) CVT_HL(1, b0.y) CVT_HL(2, b0.z) CVT_HL(3, b0.w)
      CVT_HL(4, b1.x) CVT_HL(5, b1.y) CVT_HL(6, b1.z) CVT_HL(7, b1.w)
      *(f16x8*)&hi_sm[0][r1][SWZ(r1, u31)] = ph;
      *(f16x8*)&lo_sm[0][r1][SWZ(r1, u31)] = pl;
    }
  }
  __syncthreads();

  float z_local = 0.f;   // lanes t<32: running sum of e over this lane's rows
  float pooledv[8];
#pragma unroll
  for (int j = 0; j < 8; ++j) pooledv[j] = 0.f;

  // ---- main loop: 6 uniform full tiles (rows 0..191) ----
  for (int tile = 0; tile < 6; ++tile) {
    const int cur = tile & 1;
    const int nxt = cur ^ 1;
    const int s0  = tile * TILE_S;
    const int rows_w = min(TILE_S, NS - (s0 + TILE_S));                          // 32, tile5: 8
    const int rows_i = (tile + 2 < 7) ? min(TILE_S, NS - (s0 + 2 * TILE_S)) : 0; // 32.., t4: 8, t5: 0

    // ---- MFMA: 32 rows x 32 n-cols per wave; hi+lo into same acc ----
    f32x4 acc[2][2];
    const f32x4 fzero = {0.f, 0.f, 0.f, 0.f};
#pragma unroll
    for (int mt = 0; mt < 2; ++mt)
#pragma unroll
      for (int nf = 0; nf < 2; ++nf)
        acc[mt][nf] = fzero;

#pragma unroll
    for (int kk = 0; kk < 8; ++kk) {
      // rows m16 and 16+m16 share (row&7) -> same swizzled column
      const int c = SWZ(m16, kk * 4 + quad);
      f16x8 a0h = *(const f16x8*)&hi_sm[cur][m16][c];
      f16x8 a1h = *(const f16x8*)&hi_sm[cur][16 + m16][c];
      f16x8 a0l = *(const f16x8*)&lo_sm[cur][m16][c];
      f16x8 a1l = *(const f16x8*)&lo_sm[cur][16 + m16][c];
#pragma unroll
      for (int nf = 0; nf < 2; ++nf) {
        acc[0][nf] = __builtin_amdgcn_mfma_f32_16x16x32_f16(a0h, u_frag[nf][kk], acc[0][nf], 0, 0, 0);
        acc[1][nf] = __builtin_amdgcn_mfma_f32_16x16x32_f16(a1h, u_frag[nf][kk], acc[1][nf], 0, 0, 0);
        acc[0][nf] = __builtin_amdgcn_mfma_f32_16x16x32_f16(a0l, u_frag[nf][kk], acc[0][nf], 0, 0, 0);
        acc[1][nf] = __builtin_amdgcn_mfma_f32_16x16x32_f16(a1l, u_frag[nf][kk], acc[1][nf], 0, 0, 0);
      }
    }

    // ---- p = vsum + sum_nf (-2 v[nf]) / (e^{2x}+1) (tanh identity), DPP n-reduce ----
#pragma unroll
    for (int mt = 0; mt < 2; ++mt) {
#pragma unroll
      for (int reg = 0; reg < 4; ++reg) {
        const float x0 = acc[mt][0][reg] + l_reg[0];
        const float x1 = acc[mt][1][reg] + l_reg[1];
        const float e0 = __expf(x0 + x0);
        const float e1 = __expf(x1 + x1);
        float s = vsum;
        s += __fdividef(vm2_0, e0 + 1.f);
        s += __fdividef(vm2_1, e1 + 1.f);
        s = row16_sum(s);
        if (m16 == 0)
          swave_sm[wave][mt * 16 + quad * 4 + reg] = s;
      }
    }
    __syncthreads();  // bar1: swave ready; current-tile MFMA LDS reads done

    // ---- lanes 0..31: e = exp(score) directly (all 32 rows valid) ----
    if (t < TILE_S) {
      float s = swave_sm[0][t];
#pragma unroll
      for (int w = 1; w < 8; ++w) s += swave_sm[w][t];
      const float e = __expf(s);
      e_sm[t] = e;
      z_local += e;
    }

    // ---- all waves: write pending tile (t+1) from q regs into buf[nxt] ----
    if ((t >> 5) < rows_w) {
      const int r = t >> 5;
      f16x8 ph, pl;
      CVT_HL(0, q00.x) CVT_HL(1, q00.y) CVT_HL(2, q00.z) CVT_HL(3, q00.w)
      CVT_HL(4, q01.x) CVT_HL(5, q01.y) CVT_HL(6, q01.z) CVT_HL(7, q01.w)
      *(f16x8*)&hi_sm[nxt][r][SWZ(r, u31)] = ph;
      *(f16x8*)&lo_sm[nxt][r][SWZ(r, u31)] = pl;
    }
    if (16 + (t >> 5) < rows_w) {
      const int r = 16 + (t >> 5);
      f16x8 ph, pl;
      CVT_HL(0, q10.x) CVT_HL(1, q10.y) CVT_HL(2, q10.z) CVT_HL(3, q10.w)
      CVT_HL(4, q11.x) CVT_HL(5, q11.y) CVT_HL(6, q11.z) CVT_HL(7, q11.w)
      *(f16x8*)&hi_sm[nxt][r][SWZ(r, u31)] = ph;
      *(f16x8*)&lo_sm[nxt][r][SWZ(r, u31)] = pl;
    }

    // ---- issue loads for tile t+2 (consumed next tile) ----
    if (rows_i > 0) {
      const float4* nsrc = (const float4*)(mem + ((size_t)b * NS + s0 + 2 * TILE_S) * NH);
      if ((t >> 5) < rows_i)      { q00 = nsrc[t * 2];         q01 = nsrc[t * 2 + 1]; }
      if (16 + (t >> 5) < rows_i) { q10 = nsrc[(512 + t) * 2]; q11 = nsrc[(512 + t) * 2 + 1]; }
    }
    __syncthreads();  // bar2: e_sm ready; buf[nxt] staged

    // ---- pooled: thread owns 8 h-cols x 2 rows of hi_sm[cur]; no rescale.
    //      NO bar after: staging(t+1) writes buf[cur] only after bar1(t+1). ----
    const float e0 = e_sm[2 * g];
    const float e1 = e_sm[2 * g + 1];
    const f16x8 r0 = *(const f16x8*)&hi_sm[cur][2 * g][SWZ(2 * g, u31)];
    const f16x8 r1 = *(const f16x8*)&hi_sm[cur][2 * g + 1][SWZ(2 * g + 1, u31)];
#pragma unroll
    for (int j = 0; j < 8; ++j)
      pooledv[j] = fmaf(e0, (float)r0[j], fmaf(e1, (float)r1[j], pooledv[j]));
  }

  // ---- peeled tail: tile 6, 8 valid rows in buf 0, mt=0 only, no staging ----
  {
    f32x4 acc[2];
    const f32x4 fzero = {0.f, 0.f, 0.f, 0.f};
    acc[0] = fzero; acc[1] = fzero;
#pragma unroll
    for (int kk = 0; kk < 8; ++kk) {
      const int c = SWZ(m16, kk * 4 + quad);
      f16x8 a0h = *(const f16x8*)&hi_sm[0][m16][c];
      f16x8 a0l = *(const f16x8*)&lo_sm[0][m16][c];
#pragma unroll
      for (int nf = 0; nf < 2; ++nf) {
        acc[nf] = __builtin_amdgcn_mfma_f32_16x16x32_f16(a0h, u_frag[nf][kk], acc[nf], 0, 0, 0);
        acc[nf] = __builtin_amdgcn_mfma_f32_16x16x32_f16(a0l, u_frag[nf][kk], acc[nf], 0, 0, 0);
      }
    }
#pragma unroll
    for (int reg = 0; reg < 4; ++reg) {
      const float x0 = acc[0][reg] + l_reg[0];
      const float x1 = acc[1][reg] + l_reg[1];
      const float e0 = __expf(x0 + x0);
      const float e1 = __expf(x1 + x1);
      float s = vsum;
      s += __fdividef(vm2_0, e0 + 1.f);
      s += __fdividef(vm2_1, e1 + 1.f);
      s = row16_sum(s);
      if (m16 == 0)
        swave_sm[wave][quad * 4 + reg] = s;   // rows 0..15 only
    }
    __syncthreads();  // tail bar1

    if (t < TILE_S) {
      float e = 0.f;
      if (t < 8) {      // only 8 valid rows; swave rows 8..15 are garbage-but-finite
        float s = swave_sm[0][t];
#pragma unroll
        for (int w = 1; w < 8; ++w) s += swave_sm[w][t];
        e = __expf(s);
      }
      e_sm[t] = e;
      z_local += e;
    }
    __syncthreads();  // tail bar2: e_sm ready

    const float e0 = e_sm[2 * g];
    const float e1 = e_sm[2 * g + 1];
    const f16x8 r0 = *(const f16x8*)&hi_sm[0][2 * g][SWZ(2 * g, u31)];
    const f16x8 r1 = *(const f16x8*)&hi_sm[0][2 * g + 1][SWZ(2 * g + 1, u31)];
#pragma unroll
    for (int j = 0; j < 8; ++j)
      pooledv[j] = fmaf(e0, (float)r0[j], fmaf(e1, (float)r1[j], pooledv[j]));
  }
  __syncthreads();  // final pooled reads done before scratch reuse

  // ---- epilogue: Z reduce (wave0), combine 16 replicas, normalize, project ----
  float* scratch   = (float*)&hi_sm[0][0][0];   // 16 x 264 f32 = 16.9 KB <= 32 KB hi region
  float* pooled_sm = (float*)&lo_sm[0][0][0];   // 256 f32
  if (t < TILE_S) {
    float z = z_local;
#pragma unroll
    for (int off = 1; off < 32; off <<= 1)
      z += __shfl_xor(z, off);
    if (t == 0) z_sm[0] = z;
  }
  {
    const int hblk = u31 * 8;
    f32x4 lo4 = {pooledv[0], pooledv[1], pooledv[2], pooledv[3]};
    f32x4 hi4 = {pooledv[4], pooledv[5], pooledv[6], pooledv[7]};
    *(f32x4*)&scratch[g * 264 + hblk]     = lo4;
    *(f32x4*)&scratch[g * 264 + hblk + 4] = hi4;
  }
  __syncthreads();
  const float Zi = 1.f / z_sm[0];
  if (t < NH) {
    float p = 0.f;
#pragma unroll
    for (int r = 0; r < 16; ++r)
      p += scratch[r * 264 + t];
    pooled_sm[t] = p * Zi;
  }
  __syncthreads();
  if (t < 256) {
    float s = 0.f;
#pragma unroll
    for (int i = 0; i < 4; ++i) {
      const int h = i * 64 + lane;
      s = fmaf(pooled_sm[h], MetaW[(size_t)wave * NH + h], s);
    }
#pragma unroll
    for (int off = 32; off > 0; off >>= 1)
      s += __shfl_down(s, off);
    if (lane == 0)
      out[b * 4 + wave] = s + Metab[wave];
  }
}

extern "C" void kernel_launch(void* const* d_in, const int* in_sizes, int n_in,
                              void* d_out, int out_size, void* d_ws, size_t ws_size,
                              hipStream_t stream) {
  const float* mem   = (const float*)d_in[0];
  const float* lastm = (const float*)d_in[1];
  const float* U     = (const float*)d_in[2];
  const float* W     = (const float*)d_in[3];
  const float* V     = (const float*)d_in[4];
  const float* MetaW = (const float*)d_in[5];
  const float* Metab = (const float*)d_in[6];
  float* out = (float*)d_out;
  (void)d_ws; (void)ws_size;

  hipLaunchKernelGGL(fused_attn, dim3(NB), dim3(512), 0, stream,
                     mem, lastm, U, W, V, MetaW, Metab, out);
}